// Round 10
// baseline (335.279 us; speedup 1.0000x reference)
//
#include <hip/hip_runtime.h>
#include <hip/hip_bf16.h>
#include <math.h>
#include <stdint.h>

#define NN 2048
#define DD 512
#define EE 65536
#define EPSV 0.5f
#define SEN 2048  // covered-rank sentinel (= n in the reference)

static const size_t SZ = (size_t)NN * NN;  // 4,194,304

// ---------------------------------------------------------------------------
// Build dense adjacency (f32) + row sums + CSR/CSC degrees, one edge pass.
// ---------------------------------------------------------------------------
__global__ __launch_bounds__(256) void build_adj(const int* __restrict__ row,
                                                 const int* __restrict__ col,
                                                 const float* __restrict__ attr,
                                                 float* __restrict__ adj,
                                                 float* __restrict__ rowsum,
                                                 int* __restrict__ degree,
                                                 int* __restrict__ cdeg) {
  int e = blockIdx.x * 256 + threadIdx.x;  // E exact multiple of 256
  float a = attr[e];
  int r = row[e], c = col[e];
  atomicAdd(&adj[r * NN + c], a);
  atomicAdd(&rowsum[r], a);
  atomicAdd(&degree[r], 1);
  atomicAdd(&cdeg[c], 1);
}

// ---------------------------------------------------------------------------
// Dual CSR/CSC scan + self-edge padding, both scans interleaved in ONE
// Hillis-Steele loop (half the barriers of two sequential scans). Rows padded
// to a multiple of 16 with self-edges (exact: prop_min keeps self; OR to
// self idempotent).
// ---------------------------------------------------------------------------
__global__ __launch_bounds__(1024) void csr_scan_pad(const int* __restrict__ degree,
                                                     const int* __restrict__ cdeg,
                                                     int* __restrict__ row_ptr,
                                                     int* __restrict__ fill_ptr,
                                                     int* __restrict__ col_ptr,
                                                     int* __restrict__ cfill_ptr,
                                                     unsigned short* __restrict__ colidx,
                                                     unsigned short* __restrict__ rowidx) {
  __shared__ int a[NN], b[NN], c[NN], d[NN];
  int t = threadIdx.x;
  for (int v = t; v < NN; v += 1024) {
    a[v] = (degree[v] + 15) & ~15;
    c[v] = (cdeg[v] + 15) & ~15;
  }
  __syncthreads();
  int* s1 = a; int* d1 = b; int* s2 = c; int* d2 = d;
  for (int off = 1; off < NN; off <<= 1) {
    for (int v = t; v < NN; v += 1024) {
      d1[v] = s1[v] + (v >= off ? s1[v - off] : 0);
      d2[v] = s2[v] + (v >= off ? s2[v - off] : 0);
    }
    __syncthreads();
    int* tp = s1; s1 = d1; d1 = tp;
    tp = s2; s2 = d2; d2 = tp;
  }
  for (int v = t; v < NN; v += 1024) {
    int dg = degree[v];
    int end = s1[v];
    int excl = end - ((dg + 15) & ~15);
    row_ptr[v] = excl;
    fill_ptr[v] = excl;
    for (int e = excl + dg; e < end; ++e) colidx[e] = (unsigned short)v;  // self pad
    dg = cdeg[v];
    end = s2[v];
    excl = end - ((dg + 15) & ~15);
    col_ptr[v] = excl;
    cfill_ptr[v] = excl;
    for (int e = excl + dg; e < end; ++e) rowidx[e] = (unsigned short)v;  // self pad
  }
  if (t == 0) {
    row_ptr[NN] = s1[NN - 1];
    col_ptr[NN] = s2[NN - 1];
  }
}

__global__ __launch_bounds__(256) void csr_fill(const int* __restrict__ row,
                                                const int* __restrict__ col,
                                                int* __restrict__ fill_ptr,
                                                int* __restrict__ cfill_ptr,
                                                unsigned short* __restrict__ colidx,
                                                unsigned short* __restrict__ rowidx) {
  int e = blockIdx.x * 256 + threadIdx.x;
  int r = row[e], c = col[e];
  colidx[atomicAdd(&fill_ptr[r], 1)] = (unsigned short)c;
  rowidx[atomicAdd(&cfill_ptr[c], 1)] = (unsigned short)r;
}

// ---------------------------------------------------------------------------
// Greedy maximal k-independent set (k=2), single block of 512 (8 waves).
// Round-10: 4 barriers/round (was 8):
//   A : min hop0 scatter (gate tmp!=SEN)        [bar]
//   CD: min hop1 GATHER via CSC (reads mr, writes none of mr) fused with
//       delta-detect; covered v reset dly/tmp    [bar]
//   E : OR hop0 scatter from delta gate          [bar]
//   GH: OR hop1 GATHER via CSC fused with fold + mr/tmp reset + convergence
//                                                [count-bar]
// Exact vs reference: covered nodes relay hop-0 min messages because GH
// resets their mr=SEN and A atomicMins into them; hop snapshots preserved
// because gathers never write the array they read.
// ---------------------------------------------------------------------------
__global__ __launch_bounds__(512) void mis_kernel(const int* __restrict__ row_ptr_g,
                                                  const int* __restrict__ col_ptr_g,
                                                  const unsigned short* __restrict__ colidx,
                                                  const unsigned short* __restrict__ rowidx,
                                                  const int* __restrict__ rank_g,
                                                  int* __restrict__ mis_flag,
                                                  int* __restrict__ mis_list,
                                                  int* __restrict__ misinv,
                                                  int* __restrict__ mis_count) {
  __shared__ int rank_s[NN];
  __shared__ int mr[NN];
  __shared__ int tmp[NN];
  __shared__ int cov[NN];
  __shared__ int dly[NN];
  __shared__ int mis_s[NN];
  __shared__ int row_ptr_s[NN + 1];
  __shared__ int col_ptr_s[NN + 1];
  __shared__ int cnt;
  int t = threadIdx.x;
  const uint4* col4 = (const uint4*)colidx;  // 8 u16 per uint4
  const uint4* row4 = (const uint4*)rowidx;

  for (int v = t; v < NN; v += 512) {
    int rk = rank_g[v];
    rank_s[v] = rk;
    mr[v] = rk;
    tmp[v] = rk;
    cov[v] = 0;
    mis_s[v] = 0;
    row_ptr_s[v] = row_ptr_g[v];
    col_ptr_s[v] = col_ptr_g[v];
  }
  if (t == 0) {
    row_ptr_s[NN] = row_ptr_g[NN];
    col_ptr_s[NN] = col_ptr_g[NN];
    cnt = 0;
  }
  __syncthreads();

  for (int round = 0; round < NN; ++round) {
    // --- A: min hop0 scatter from uncovered sources ---
    for (int v = t; v < NN; v += 512) {
      int val = tmp[v];
      if (val != SEN) {
        int e0 = row_ptr_s[v];
        int nch = (row_ptr_s[v + 1] - e0) >> 3;
        const uint4* b4 = col4 + (e0 >> 3);
        for (int cI = 0; cI < nch; cI += 2) {
          uint4 A = b4[cI], B = b4[cI + 1];
          atomicMin(&mr[A.x & 0xFFFFu], val); atomicMin(&mr[A.x >> 16], val);
          atomicMin(&mr[A.y & 0xFFFFu], val); atomicMin(&mr[A.y >> 16], val);
          atomicMin(&mr[A.z & 0xFFFFu], val); atomicMin(&mr[A.z >> 16], val);
          atomicMin(&mr[A.w & 0xFFFFu], val); atomicMin(&mr[A.w >> 16], val);
          atomicMin(&mr[B.x & 0xFFFFu], val); atomicMin(&mr[B.x >> 16], val);
          atomicMin(&mr[B.y & 0xFFFFu], val); atomicMin(&mr[B.y >> 16], val);
          atomicMin(&mr[B.z & 0xFFFFu], val); atomicMin(&mr[B.z >> 16], val);
          atomicMin(&mr[B.w & 0xFFFFu], val); atomicMin(&mr[B.w >> 16], val);
        }
      }
    }
    __syncthreads();
    // --- CD: min hop1 gather (CSC) + delta detect; no mr writes ---
    for (int v = t; v < NN; v += 512) {
      if (!cov[v]) {
        int val = mr[v];
        int e0 = col_ptr_s[v];
        int nch = (col_ptr_s[v + 1] - e0) >> 3;
        const uint4* b4 = row4 + (e0 >> 3);
        for (int cI = 0; cI < nch; cI += 2) {
          uint4 A = b4[cI], B = b4[cI + 1];
          int m0 = min(mr[A.x & 0xFFFFu], mr[A.x >> 16]);
          int m1 = min(mr[A.y & 0xFFFFu], mr[A.y >> 16]);
          int m2 = min(mr[A.z & 0xFFFFu], mr[A.z >> 16]);
          int m3 = min(mr[A.w & 0xFFFFu], mr[A.w >> 16]);
          int m4 = min(mr[B.x & 0xFFFFu], mr[B.x >> 16]);
          int m5 = min(mr[B.y & 0xFFFFu], mr[B.y >> 16]);
          int m6 = min(mr[B.z & 0xFFFFu], mr[B.z >> 16]);
          int m7 = min(mr[B.w & 0xFFFFu], mr[B.w >> 16]);
          val = min(val, min(min(min(m0, m1), min(m2, m3)),
                             min(min(m4, m5), min(m6, m7))));
        }
        int nw = (rank_s[v] == val) ? 1 : 0;
        if (nw) mis_s[v] = 1;
        dly[v] = nw;
        tmp[v] = nw;
      } else {
        dly[v] = 0;
        tmp[v] = 0;
      }
    }
    __syncthreads();
    // --- E: OR hop0 scatter from delta gate ---
    for (int v = t; v < NN; v += 512) {
      if (tmp[v]) {
        int e0 = row_ptr_s[v];
        int nch = (row_ptr_s[v + 1] - e0) >> 3;
        const uint4* b4 = col4 + (e0 >> 3);
        for (int cI = 0; cI < nch; cI += 2) {
          uint4 A = b4[cI], B = b4[cI + 1];
          dly[A.x & 0xFFFFu] = 1; dly[A.x >> 16] = 1;
          dly[A.y & 0xFFFFu] = 1; dly[A.y >> 16] = 1;
          dly[A.z & 0xFFFFu] = 1; dly[A.z >> 16] = 1;
          dly[A.w & 0xFFFFu] = 1; dly[A.w >> 16] = 1;
          dly[B.x & 0xFFFFu] = 1; dly[B.x >> 16] = 1;
          dly[B.y & 0xFFFFu] = 1; dly[B.y >> 16] = 1;
          dly[B.z & 0xFFFFu] = 1; dly[B.z >> 16] = 1;
          dly[B.w & 0xFFFFu] = 1; dly[B.w >> 16] = 1;
        }
      }
    }
    __syncthreads();
    // --- GH: OR hop1 gather (CSC) + fold + mr/tmp reset + convergence ---
    int mypred = 0;
    for (int v = t; v < NN; v += 512) {
      if (!cov[v]) {
        int c1 = dly[v];
        if (!c1) {
          int e0 = col_ptr_s[v];
          int nch = (col_ptr_s[v + 1] - e0) >> 3;
          const uint4* b4 = row4 + (e0 >> 3);
          for (int cI = 0; cI < nch; cI += 2) {
            uint4 A = b4[cI], B = b4[cI + 1];
            c1 |= dly[A.x & 0xFFFFu] | dly[A.x >> 16] |
                  dly[A.y & 0xFFFFu] | dly[A.y >> 16] |
                  dly[A.z & 0xFFFFu] | dly[A.z >> 16] |
                  dly[A.w & 0xFFFFu] | dly[A.w >> 16] |
                  dly[B.x & 0xFFFFu] | dly[B.x >> 16] |
                  dly[B.y & 0xFFFFu] | dly[B.y >> 16] |
                  dly[B.z & 0xFFFFu] | dly[B.z >> 16] |
                  dly[B.w & 0xFFFFu] | dly[B.w >> 16];
            if (c1) break;
          }
        }
        cov[v] = c1;
        int nmr = c1 ? SEN : rank_s[v];
        mr[v] = nmr;
        tmp[v] = nmr;
        mypred |= (c1 == 0);
      } else {
        mr[v] = SEN;  // reset relay state clobbered by A's scatter
        tmp[v] = SEN;
      }
    }
    if (__syncthreads_count(mypred) == 0) break;
  }

  for (int v = t; v < NN; v += 512) {
    int s = mis_s[v];
    mis_flag[v] = s;
    int slot = -1;
    if (s) {
      slot = atomicAdd(&cnt, 1);  // unordered: all consumers order-free
      mis_list[slot] = v;
    }
    misinv[v] = slot;
  }
  __syncthreads();
  if (t == 0) *mis_count = cnt;
}

// ---------------------------------------------------------------------------
// adj -> rw in place, fused with MIS-column gather into compact Bc.
// ---------------------------------------------------------------------------
__global__ __launch_bounds__(256) void rw_transform_gather(float* __restrict__ adj,
                                                           const float* __restrict__ rowsum,
                                                           const int* __restrict__ misinv,
                                                           float* __restrict__ Bc) {
  int idx = blockIdx.x * 256 + threadIdx.x;  // over N*N
  int i = idx >> 11, j = idx & (NN - 1);
  float s = rowsum[i];
  s = (s > 0.f) ? s : 1.f;
  float v = adj[idx] / s;
  v = (i == j) ? (v + EPSV) : (v * (1.f - EPSV));
  adj[idx] = v;
  int tc = misinv[j];
  if (tc >= 0) Bc[(size_t)tc * NN + i] = v;
}

// ---------------------------------------------------------------------------
// Fused c2 + Gumbel-argmax. 16 columns per block: each of the 4 waves holds
// 4 columns in registers; ALL waves stream the SAME 32 rows so the 8KB row
// loads L1-hit for ~3 of 4 waves. A-traffic = M/16 colgroups x 16MB ~ 280MB
// (4x less than round 9). Deterministic shuffle tree; winner via u64
// atomicMax: key = mono(logit)<<32 | (2047-m) -> np.argmax first-occurrence
// ties; sentinel 0 row -> cluster 0.
// ---------------------------------------------------------------------------
__device__ inline unsigned int f32_key(float x) {
  unsigned int u = __float_as_uint(x);
  return (u & 0x80000000u) ? ~u : (u | 0x80000000u);
}
__device__ inline float dot4(float4 a, float4 b) {
  return ((a.x * b.x + a.y * b.y) + (a.z * b.z + a.w * b.w));
}
__device__ inline unsigned long long umax64(unsigned long long a, unsigned long long b) {
  return a > b ? a : b;
}
__device__ inline int pdecode(unsigned long long p) {
  return (p == 0ull) ? 0 : (NN - 1 - (int)(p & 0xFFFFFFFFull));
}

__global__ __launch_bounds__(256) void c2_argmax(const float* __restrict__ rw,
                                                 const float* __restrict__ Bc,
                                                 const float* __restrict__ u,
                                                 const int* __restrict__ mis_list,
                                                 const int* __restrict__ mis_count,
                                                 unsigned long long* __restrict__ packed) {
  int M = *mis_count;
  int ncg = (M + 15) >> 4;
  int njobs = ncg * 64;  // 64 tiles of 32 rows
  int lane = threadIdx.x & 63, w = threadIdx.x >> 6;
  for (int j = blockIdx.x; j < njobs; j += gridDim.x) {
    int cg = j >> 6, tile = j & 63;
    int c0 = cg * 16 + w * 4;  // this wave's 4 columns
    float4 creg[4][8];
    int mcol[4];
#pragma unroll
    for (int cc = 0; cc < 4; ++cc) {
      int colv = c0 + cc;
      int cl = colv < M ? colv : (M - 1);
      mcol[cc] = mis_list[cl];
      const float4* cb = (const float4*)(Bc + (size_t)cl * NN);
#pragma unroll
      for (int q = 0; q < 8; ++q) creg[cc][q] = cb[q * 64 + lane];
    }
    int rbase = tile * 32;
#pragma unroll 2
    for (int it = 0; it < 32; ++it) {
      int r = rbase + it;
      const float4* rp = (const float4*)(rw + (size_t)r * NN);
      float4 a0 = rp[lane], a1 = rp[64 + lane], a2 = rp[128 + lane], a3 = rp[192 + lane];
      float4 a4 = rp[256 + lane], a5 = rp[320 + lane], a6 = rp[384 + lane], a7 = rp[448 + lane];
      float sacc[4];
#pragma unroll
      for (int cc = 0; cc < 4; ++cc) {
        float s01 = dot4(a0, creg[cc][0]) + dot4(a1, creg[cc][1]);
        float s23 = dot4(a2, creg[cc][2]) + dot4(a3, creg[cc][3]);
        float s45 = dot4(a4, creg[cc][4]) + dot4(a5, creg[cc][5]);
        float s67 = dot4(a6, creg[cc][6]) + dot4(a7, creg[cc][7]);
        float s = (s01 + s23) + (s45 + s67);
        s += __shfl_xor(s, 32);
        s += __shfl_xor(s, 16);
        s += __shfl_xor(s, 8);
        s += __shfl_xor(s, 4);
        s += __shfl_xor(s, 2);
        s += __shfl_xor(s, 1);
        sacc[cc] = s;
      }
      if (lane == 0) {
        unsigned long long best = 0ull;
#pragma unroll
        for (int cc = 0; cc < 4; ++cc) {
          if (c0 + cc < M && sacc[cc] > 0.f) {
            int m = mcol[cc];
            float uu = u[(size_t)r * NN + m];
            float g = -logf(-logf(uu + 1e-20f) + 1e-20f);
            float logit = logf(sacc[cc]) + g;
            unsigned long long key =
                ((unsigned long long)f32_key(logit) << 32) | (unsigned int)(NN - 1 - m);
            best = umax64(best, key);
          }
        }
        if (best) atomicMax(&packed[r], best);
      }
    }
  }
}

// ---------------------------------------------------------------------------
// Fused: inline winner decode + cluster/counts production + adj_c edge
// scatter + x_pool scatter (cluster_decode dispatch deleted).
// ---------------------------------------------------------------------------
__global__ __launch_bounds__(256) void scatter_fused(const int* __restrict__ row,
                                                     const int* __restrict__ col,
                                                     const float* __restrict__ attr,
                                                     const float* __restrict__ x,
                                                     const unsigned long long* __restrict__ packed,
                                                     int* __restrict__ cluster,
                                                     int* __restrict__ counts,
                                                     float* __restrict__ adjc,
                                                     float* __restrict__ xp) {
  int idx = blockIdx.x * 256 + threadIdx.x;  // over N*D (= 1,048,576)
  int i = idx >> 9;
  int ci = pdecode(packed[i]);  // broadcast read within each 512-thread row group
  if ((idx & 511) == 0) {
    cluster[i] = ci;
    atomicAdd(&counts[ci], 1);
  }
  if (idx < EE) {
    int cr = pdecode(packed[row[idx]]);
    int cc = pdecode(packed[col[idx]]);
    atomicAdd(&adjc[(size_t)cr * NN + cc], attr[idx]);
  }
  atomicAdd(&xp[ci * DD + (idx & (DD - 1))], x[idx]);
}

// ---------------------------------------------------------------------------
// c_hard, p_inv, mis, and x_pool scaling in one pass.
// ---------------------------------------------------------------------------
__global__ __launch_bounds__(256) void write_chpm(const int* __restrict__ cluster,
                                                  const int* __restrict__ counts,
                                                  const int* __restrict__ mis_flag,
                                                  float* __restrict__ out_ch,
                                                  float* __restrict__ out_pinv,
                                                  float* __restrict__ out_mis,
                                                  float* __restrict__ out_xp) {
  int idx = blockIdx.x * 256 + threadIdx.x;  // over N*N
  int a = idx >> 11, b = idx & (NN - 1);
  out_ch[idx] = (cluster[a] == b) ? 1.f : 0.f;
  float pv = 0.f;
  if (cluster[b] == a) {
    int c = counts[a];
    pv = 1.f / (float)(c > 0 ? c : 1);
  }
  out_pinv[idx] = pv;
  if (idx < NN) out_mis[idx] = mis_flag[idx] ? 1.f : 0.f;
  if (idx < NN * DD) {
    int c = counts[idx >> 9];
    out_xp[idx] = out_xp[idx] / (float)(c > 0 ? c : 1);
  }
}

// ---------------------------------------------------------------------------
extern "C" void kernel_launch(void* const* d_in, const int* in_sizes, int n_in,
                              void* d_out, int out_size, void* d_ws, size_t ws_size,
                              hipStream_t stream) {
  const int*   edge_index = (const int*)d_in[0];
  const float* edge_attr  = (const float*)d_in[1];
  const float* x          = (const float*)d_in[2];
  const int*   rank       = (const int*)d_in[3];
  const float* u          = (const float*)d_in[4];
  float* out              = (float*)d_out;  // f32 outputs, concatenated

  const int* row = edge_index;
  const int* col = edge_index + EE;

  float* out_adjc = out;                 // N*N — doubles as adj/rw scratch
  float* out_ch   = out + SZ;            // N*N — doubles as Bc scratch
  float* out_pinv = out + 2 * SZ;        // N*N
  float* out_mis  = out + 3 * SZ;        // N
  float* out_xp   = out + 3 * SZ + NN;   // N*D

  // d_ws layout (~490 KB). First 5 arrays zeroed; rest fully written.
  unsigned long long* packed = (unsigned long long*)d_ws;  // N u64 (zeroed)
  float* rowsum    = (float*)(packed + NN);        // N  (zeroed)
  int*   counts    = (int*)(rowsum + NN);          // N  (zeroed)
  int*   degree    = counts + NN;                  // N  (zeroed)
  int*   cdeg      = degree + NN;                  // N  (zeroed)
  int*   mis_flag  = cdeg + NN;                    // N
  int*   cluster   = mis_flag + NN;                // N
  int*   mis_list  = cluster + NN;                 // N
  int*   misinv    = mis_list + NN;                // N
  int*   mis_count = misinv + NN;                  // 1
  int*   fill_ptr  = mis_count + 1;                // N
  int*   cfill_ptr = fill_ptr + NN;                // N
  int*   row_ptr   = cfill_ptr + NN;               // N+1
  int*   col_ptr   = row_ptr + NN + 1;             // N+1
  unsigned short* colidx =                          // padded E (<=98304) u16, 32B-aligned
      (unsigned short*)(((uintptr_t)(col_ptr + NN + 1) + 31) & ~(uintptr_t)31);
  unsigned short* rowidx = colidx + 98304;         // padded E u16 (32B-aligned)

  hipMemsetAsync(out_adjc, 0, SZ * sizeof(float), stream);
  hipMemsetAsync(out_xp, 0, (size_t)NN * DD * sizeof(float), stream);
  hipMemsetAsync(d_ws, 0, NN * sizeof(unsigned long long) + 4 * NN * sizeof(int), stream);

  build_adj<<<EE / 256, 256, 0, stream>>>(row, col, edge_attr, out_adjc, rowsum, degree, cdeg);
  csr_scan_pad<<<1, 1024, 0, stream>>>(degree, cdeg, row_ptr, fill_ptr, col_ptr, cfill_ptr,
                                       colidx, rowidx);
  csr_fill<<<EE / 256, 256, 0, stream>>>(row, col, fill_ptr, cfill_ptr, colidx, rowidx);
  mis_kernel<<<1, 512, 0, stream>>>(row_ptr, col_ptr, colidx, rowidx, rank,
                                    mis_flag, mis_list, misinv, mis_count);
  rw_transform_gather<<<(NN * NN) / 256, 256, 0, stream>>>(out_adjc, rowsum, misinv, out_ch);
  c2_argmax<<<1024, 256, 0, stream>>>(out_adjc, out_ch, u, mis_list, mis_count, packed);

  // rw no longer needed: rewrite the region with the real adj_c
  hipMemsetAsync(out_adjc, 0, SZ * sizeof(float), stream);
  scatter_fused<<<(NN * DD) / 256, 256, 0, stream>>>(row, col, edge_attr, x, packed,
                                                     cluster, counts, out_adjc, out_xp);

  write_chpm<<<(NN * NN) / 256, 256, 0, stream>>>(cluster, counts, mis_flag,
                                                  out_ch, out_pinv, out_mis, out_xp);
}

// Round 11
// 265.173 us; speedup vs baseline: 1.2644x; 1.2644x over previous
//
#include <hip/hip_runtime.h>
#include <hip/hip_bf16.h>
#include <math.h>
#include <stdint.h>

#define NN 2048
#define DD 512
#define EE 65536
#define EPSV 0.5f
#define SEN 2048  // covered-rank sentinel (= n in the reference)

static const size_t SZ = (size_t)NN * NN;  // 4,194,304

// ---------------------------------------------------------------------------
// Build dense adjacency (f32) + row sums + CSR/CSC degrees, one edge pass.
// ---------------------------------------------------------------------------
__global__ __launch_bounds__(256) void build_adj(const int* __restrict__ row,
                                                 const int* __restrict__ col,
                                                 const float* __restrict__ attr,
                                                 float* __restrict__ adj,
                                                 float* __restrict__ rowsum,
                                                 int* __restrict__ degree,
                                                 int* __restrict__ cdeg) {
  int e = blockIdx.x * 256 + threadIdx.x;  // E exact multiple of 256
  float a = attr[e];
  int r = row[e], c = col[e];
  atomicAdd(&adj[r * NN + c], a);
  atomicAdd(&rowsum[r], a);
  atomicAdd(&degree[r], 1);
  atomicAdd(&cdeg[c], 1);
}

// ---------------------------------------------------------------------------
// Dual CSR/CSC scan + self-edge padding, both scans interleaved in ONE
// Hillis-Steele loop. Rows padded to a multiple of 16 with self-edges
// (exact: prop_min keeps self; OR to self idempotent).
// ---------------------------------------------------------------------------
__global__ __launch_bounds__(1024) void csr_scan_pad(const int* __restrict__ degree,
                                                     const int* __restrict__ cdeg,
                                                     int* __restrict__ row_ptr,
                                                     int* __restrict__ fill_ptr,
                                                     int* __restrict__ col_ptr,
                                                     int* __restrict__ cfill_ptr,
                                                     unsigned short* __restrict__ colidx,
                                                     unsigned short* __restrict__ rowidx) {
  __shared__ int a[NN], b[NN], c[NN], d[NN];
  int t = threadIdx.x;
  for (int v = t; v < NN; v += 1024) {
    a[v] = (degree[v] + 15) & ~15;
    c[v] = (cdeg[v] + 15) & ~15;
  }
  __syncthreads();
  int* s1 = a; int* d1 = b; int* s2 = c; int* d2 = d;
  for (int off = 1; off < NN; off <<= 1) {
    for (int v = t; v < NN; v += 1024) {
      d1[v] = s1[v] + (v >= off ? s1[v - off] : 0);
      d2[v] = s2[v] + (v >= off ? s2[v - off] : 0);
    }
    __syncthreads();
    int* tp = s1; s1 = d1; d1 = tp;
    tp = s2; s2 = d2; d2 = tp;
  }
  for (int v = t; v < NN; v += 1024) {
    int dg = degree[v];
    int end = s1[v];
    int excl = end - ((dg + 15) & ~15);
    row_ptr[v] = excl;
    fill_ptr[v] = excl;
    for (int e = excl + dg; e < end; ++e) colidx[e] = (unsigned short)v;  // self pad
    dg = cdeg[v];
    end = s2[v];
    excl = end - ((dg + 15) & ~15);
    col_ptr[v] = excl;
    cfill_ptr[v] = excl;
    for (int e = excl + dg; e < end; ++e) rowidx[e] = (unsigned short)v;  // self pad
  }
  if (t == 0) {
    row_ptr[NN] = s1[NN - 1];
    col_ptr[NN] = s2[NN - 1];
  }
}

__global__ __launch_bounds__(256) void csr_fill(const int* __restrict__ row,
                                                const int* __restrict__ col,
                                                int* __restrict__ fill_ptr,
                                                int* __restrict__ cfill_ptr,
                                                unsigned short* __restrict__ colidx,
                                                unsigned short* __restrict__ rowidx) {
  int e = blockIdx.x * 256 + threadIdx.x;
  int r = row[e], c = col[e];
  colidx[atomicAdd(&fill_ptr[r], 1)] = (unsigned short)c;
  rowidx[atomicAdd(&cfill_ptr[c], 1)] = (unsigned short)r;
}

// ---------------------------------------------------------------------------
// Greedy maximal k-independent set (k=2), single block, state in LDS.
// Round-11: WORKLIST sweeps. Every former gated full-array sweep (the
// per-round latency cost: ~4 sweeps x 2048 gate reads) becomes a compact
// list iteration:
//   unc[cur]: uncovered vertices (rebuilt each round, double-buffered)
//   dl      : this round's delta (newly selected MIS nodes)
// Phases per round (5 barriers):
//   R0: full-array batched reset (mr = cov?SEN:rank, dly=0) — pure stores
//   A : min hop0 scatter from unc (relay-through-covered preserved: R0 set
//       covered mr=SEN and A atomicMins hop-0 values into them)
//   CD: min hop1 gather over CSC at unc + delta detect (+ dl append)
//   E : OR hop0 scatter from dl (dly[delta]=1 set in CD = "keep self")
//   GH: OR hop1 gather over CSC at unc + fold + rebuild unc[cur^1]
// Exact vs reference: list membership == the old gates; delta-OR exactness
// (monotone mask + union homomorphism) unchanged; hop snapshots preserved
// (gathers never write the array they read).
// ---------------------------------------------------------------------------
__global__ __launch_bounds__(1024) void mis_kernel(const int* __restrict__ row_ptr_g,
                                                   const int* __restrict__ col_ptr_g,
                                                   const unsigned short* __restrict__ colidx,
                                                   const unsigned short* __restrict__ rowidx,
                                                   const int* __restrict__ rank_g,
                                                   int* __restrict__ mis_flag,
                                                   int* __restrict__ mis_list,
                                                   int* __restrict__ misinv,
                                                   int* __restrict__ mis_count) {
  __shared__ int rank_s[NN];
  __shared__ int mr[NN];
  __shared__ int cov[NN];
  __shared__ int dly[NN];
  __shared__ int mis_s[NN];
  __shared__ int row_ptr_s[NN + 1];
  __shared__ int col_ptr_s[NN + 1];
  __shared__ int unc[2][NN];
  __shared__ int dl[NN];
  __shared__ int ucnt[2];
  __shared__ int dcnt;
  __shared__ int cnt;
  int t = threadIdx.x;
  const uint4* col4 = (const uint4*)colidx;  // 8 u16 per uint4
  const uint4* row4 = (const uint4*)rowidx;

  for (int v = t; v < NN; v += 1024) {
    int rk = rank_g[v];
    rank_s[v] = rk;
    mr[v] = rk;
    cov[v] = 0;
    dly[v] = 0;
    mis_s[v] = 0;
    row_ptr_s[v] = row_ptr_g[v];
    col_ptr_s[v] = col_ptr_g[v];
    unc[0][v] = v;  // round-0 uncovered list = all vertices (ordered)
  }
  if (t == 0) {
    row_ptr_s[NN] = row_ptr_g[NN];
    col_ptr_s[NN] = col_ptr_g[NN];
    ucnt[0] = NN;
    ucnt[1] = 0;
    dcnt = 0;
    cnt = 0;
  }
  __syncthreads();

  int cur = 0;
  for (int round = 0; round < NN; ++round) {
    int U = ucnt[cur];
    // --- R0: batched reset (skippable work for round 0, but cheap/uniform) ---
    if (round) {
      for (int v = t; v < NN; v += 1024) {
        mr[v] = cov[v] ? SEN : rank_s[v];
        dly[v] = 0;
      }
      if (t == 0) { ucnt[cur ^ 1] = 0; dcnt = 0; }
      __syncthreads();
    }
    // --- A: min hop0 scatter from uncovered sources ---
    for (int i = t; i < U; i += 1024) {
      int v = unc[cur][i];
      int val = rank_s[v];
      int e0 = row_ptr_s[v];
      int nch = (row_ptr_s[v + 1] - e0) >> 3;
      const uint4* b4 = col4 + (e0 >> 3);
      for (int cI = 0; cI < nch; cI += 2) {
        uint4 A = b4[cI], B = b4[cI + 1];
        atomicMin(&mr[A.x & 0xFFFFu], val); atomicMin(&mr[A.x >> 16], val);
        atomicMin(&mr[A.y & 0xFFFFu], val); atomicMin(&mr[A.y >> 16], val);
        atomicMin(&mr[A.z & 0xFFFFu], val); atomicMin(&mr[A.z >> 16], val);
        atomicMin(&mr[A.w & 0xFFFFu], val); atomicMin(&mr[A.w >> 16], val);
        atomicMin(&mr[B.x & 0xFFFFu], val); atomicMin(&mr[B.x >> 16], val);
        atomicMin(&mr[B.y & 0xFFFFu], val); atomicMin(&mr[B.y >> 16], val);
        atomicMin(&mr[B.z & 0xFFFFu], val); atomicMin(&mr[B.z >> 16], val);
        atomicMin(&mr[B.w & 0xFFFFu], val); atomicMin(&mr[B.w >> 16], val);
      }
    }
    __syncthreads();
    // --- CD: min hop1 gather (CSC) + delta detect + dl append ---
    for (int i = t; i < U; i += 1024) {
      int v = unc[cur][i];
      int val = mr[v];
      int e0 = col_ptr_s[v];
      int nch = (col_ptr_s[v + 1] - e0) >> 3;
      const uint4* b4 = row4 + (e0 >> 3);
      for (int cI = 0; cI < nch; cI += 2) {
        uint4 A = b4[cI], B = b4[cI + 1];
        int m0 = min(mr[A.x & 0xFFFFu], mr[A.x >> 16]);
        int m1 = min(mr[A.y & 0xFFFFu], mr[A.y >> 16]);
        int m2 = min(mr[A.z & 0xFFFFu], mr[A.z >> 16]);
        int m3 = min(mr[A.w & 0xFFFFu], mr[A.w >> 16]);
        int m4 = min(mr[B.x & 0xFFFFu], mr[B.x >> 16]);
        int m5 = min(mr[B.y & 0xFFFFu], mr[B.y >> 16]);
        int m6 = min(mr[B.z & 0xFFFFu], mr[B.z >> 16]);
        int m7 = min(mr[B.w & 0xFFFFu], mr[B.w >> 16]);
        val = min(val, min(min(min(m0, m1), min(m2, m3)),
                           min(min(m4, m5), min(m6, m7))));
      }
      if (rank_s[v] == val) {  // newly selected
        mis_s[v] = 1;
        dly[v] = 1;  // "keep self" of OR hop0
        dl[atomicAdd(&dcnt, 1)] = v;  // unordered append (consumers order-free)
      }
    }
    __syncthreads();
    // --- E: OR hop0 scatter from delta ---
    int D = dcnt;
    for (int i = t; i < D; i += 1024) {
      int v = dl[i];
      int e0 = row_ptr_s[v];
      int nch = (row_ptr_s[v + 1] - e0) >> 3;
      const uint4* b4 = col4 + (e0 >> 3);
      for (int cI = 0; cI < nch; cI += 2) {
        uint4 A = b4[cI], B = b4[cI + 1];
        dly[A.x & 0xFFFFu] = 1; dly[A.x >> 16] = 1;
        dly[A.y & 0xFFFFu] = 1; dly[A.y >> 16] = 1;
        dly[A.z & 0xFFFFu] = 1; dly[A.z >> 16] = 1;
        dly[A.w & 0xFFFFu] = 1; dly[A.w >> 16] = 1;
        dly[B.x & 0xFFFFu] = 1; dly[B.x >> 16] = 1;
        dly[B.y & 0xFFFFu] = 1; dly[B.y >> 16] = 1;
        dly[B.z & 0xFFFFu] = 1; dly[B.z >> 16] = 1;
        dly[B.w & 0xFFFFu] = 1; dly[B.w >> 16] = 1;
      }
    }
    __syncthreads();
    // --- GH: OR hop1 gather (CSC) + fold + rebuild survivor list ---
    for (int i = t; i < U; i += 1024) {
      int v = unc[cur][i];
      int c1 = dly[v];
      if (!c1) {
        int e0 = col_ptr_s[v];
        int nch = (col_ptr_s[v + 1] - e0) >> 3;
        const uint4* b4 = row4 + (e0 >> 3);
        for (int cI = 0; cI < nch; cI += 2) {
          uint4 A = b4[cI], B = b4[cI + 1];
          c1 |= dly[A.x & 0xFFFFu] | dly[A.x >> 16] |
                dly[A.y & 0xFFFFu] | dly[A.y >> 16] |
                dly[A.z & 0xFFFFu] | dly[A.z >> 16] |
                dly[A.w & 0xFFFFu] | dly[A.w >> 16] |
                dly[B.x & 0xFFFFu] | dly[B.x >> 16] |
                dly[B.y & 0xFFFFu] | dly[B.y >> 16] |
                dly[B.z & 0xFFFFu] | dly[B.z >> 16] |
                dly[B.w & 0xFFFFu] | dly[B.w >> 16];
          if (c1) break;
        }
      }
      if (c1) cov[v] = 1;
      else unc[cur ^ 1][atomicAdd(&ucnt[cur ^ 1], 1)] = v;  // unordered survivor
    }
    __syncthreads();
    if (ucnt[cur ^ 1] == 0) break;  // uniform post-barrier read
    cur ^= 1;
  }

  for (int v = t; v < NN; v += 1024) {
    int s = mis_s[v];
    mis_flag[v] = s;
    int slot = -1;
    if (s) {
      slot = atomicAdd(&cnt, 1);  // unordered: all consumers order-free
      mis_list[slot] = v;
    }
    misinv[v] = slot;
  }
  __syncthreads();
  if (t == 0) *mis_count = cnt;
}

// ---------------------------------------------------------------------------
// adj -> rw in place, fused with MIS-column gather into compact Bc.
// ---------------------------------------------------------------------------
__global__ __launch_bounds__(256) void rw_transform_gather(float* __restrict__ adj,
                                                           const float* __restrict__ rowsum,
                                                           const int* __restrict__ misinv,
                                                           float* __restrict__ Bc) {
  int idx = blockIdx.x * 256 + threadIdx.x;  // over N*N
  int i = idx >> 11, j = idx & (NN - 1);
  float s = rowsum[i];
  s = (s > 0.f) ? s : 1.f;
  float v = adj[idx] / s;
  v = (i == j) ? (v + EPSV) : (v * (1.f - EPSV));
  adj[idx] = v;
  int tc = misinv[j];
  if (tc >= 0) Bc[(size_t)tc * NN + i] = v;
}

// ---------------------------------------------------------------------------
// Fused c2 + Gumbel-argmax — ROUND-9 form (4 cols/job, 1024 blocks; the
// round-10 16-col variant halved grid parallelism and regressed).
// ---------------------------------------------------------------------------
__device__ inline unsigned int f32_key(float x) {
  unsigned int u = __float_as_uint(x);
  return (u & 0x80000000u) ? ~u : (u | 0x80000000u);
}
__device__ inline float dot4(float4 a, float4 b) {
  return ((a.x * b.x + a.y * b.y) + (a.z * b.z + a.w * b.w));
}
__device__ inline unsigned long long umax64(unsigned long long a, unsigned long long b) {
  return a > b ? a : b;
}

__global__ __launch_bounds__(256) void c2_argmax(const float* __restrict__ rw,
                                                 const float* __restrict__ Bc,
                                                 const float* __restrict__ u,
                                                 const int* __restrict__ mis_list,
                                                 const int* __restrict__ mis_count,
                                                 unsigned long long* __restrict__ packed) {
  int M = *mis_count;
  int ncg = (M + 3) >> 2;
  int njobs = ncg * 64;  // 64 tiles of 32 rows
  int lane = threadIdx.x & 63, w = threadIdx.x >> 6;
  for (int j = blockIdx.x; j < njobs; j += gridDim.x) {
    int cg = j >> 6, tile = j & 63;
    int c0 = cg * 4;
    float4 creg[4][8];
    int mcol[4];
#pragma unroll
    for (int cc = 0; cc < 4; ++cc) {
      int colv = c0 + cc;
      int cl = colv < M ? colv : (M - 1);
      mcol[cc] = mis_list[cl];
      const float4* cb = (const float4*)(Bc + (size_t)cl * NN);
#pragma unroll
      for (int q = 0; q < 8; ++q) creg[cc][q] = cb[q * 64 + lane];
    }
    int rbase = tile * 32 + w * 8;
#pragma unroll
    for (int it = 0; it < 8; ++it) {
      int r = rbase + it;
      const float4* rp = (const float4*)(rw + (size_t)r * NN);
      float4 a0 = rp[lane], a1 = rp[64 + lane], a2 = rp[128 + lane], a3 = rp[192 + lane];
      float4 a4 = rp[256 + lane], a5 = rp[320 + lane], a6 = rp[384 + lane], a7 = rp[448 + lane];
      float sacc[4];
#pragma unroll
      for (int cc = 0; cc < 4; ++cc) {
        float s01 = dot4(a0, creg[cc][0]) + dot4(a1, creg[cc][1]);
        float s23 = dot4(a2, creg[cc][2]) + dot4(a3, creg[cc][3]);
        float s45 = dot4(a4, creg[cc][4]) + dot4(a5, creg[cc][5]);
        float s67 = dot4(a6, creg[cc][6]) + dot4(a7, creg[cc][7]);
        float s = (s01 + s23) + (s45 + s67);
        s += __shfl_xor(s, 32);
        s += __shfl_xor(s, 16);
        s += __shfl_xor(s, 8);
        s += __shfl_xor(s, 4);
        s += __shfl_xor(s, 2);
        s += __shfl_xor(s, 1);
        sacc[cc] = s;
      }
      if (lane == 0) {
        unsigned long long best = 0ull;
#pragma unroll
        for (int cc = 0; cc < 4; ++cc) {
          if (c0 + cc < M && sacc[cc] > 0.f) {
            int m = mcol[cc];
            float uu = u[(size_t)r * NN + m];
            float g = -logf(-logf(uu + 1e-20f) + 1e-20f);
            float logit = logf(sacc[cc]) + g;
            unsigned long long key =
                ((unsigned long long)f32_key(logit) << 32) | (unsigned int)(NN - 1 - m);
            best = umax64(best, key);
          }
        }
        if (best) atomicMax(&packed[r], best);
      }
    }
  }
}

// ---------------------------------------------------------------------------
__global__ __launch_bounds__(256) void cluster_decode(const unsigned long long* __restrict__ packed,
                                                      int* __restrict__ cluster,
                                                      int* __restrict__ counts) {
  int i = blockIdx.x * 256 + threadIdx.x;
  unsigned long long p = packed[i];
  int m = (p == 0ull) ? 0 : (NN - 1 - (int)(p & 0xFFFFFFFFull));
  cluster[i] = m;
  atomicAdd(&counts[m], 1);
}

// ---------------------------------------------------------------------------
// Fused adj_c edge scatter + x_pool scatter (round-9 form).
// ---------------------------------------------------------------------------
__global__ __launch_bounds__(256) void scatter_fused(const int* __restrict__ row,
                                                     const int* __restrict__ col,
                                                     const float* __restrict__ attr,
                                                     const float* __restrict__ x,
                                                     const int* __restrict__ cluster,
                                                     float* __restrict__ adjc,
                                                     float* __restrict__ xp) {
  int idx = blockIdx.x * 256 + threadIdx.x;  // over N*D (= 1,048,576)
  if (idx < EE) {
    int cr = cluster[row[idx]], cc = cluster[col[idx]];
    atomicAdd(&adjc[(size_t)cr * NN + cc], attr[idx]);
  }
  int i = idx >> 9;
  atomicAdd(&xp[cluster[i] * DD + (idx & (DD - 1))], x[idx]);
}

// ---------------------------------------------------------------------------
// c_hard, p_inv, mis, and x_pool scaling in one pass.
// ---------------------------------------------------------------------------
__global__ __launch_bounds__(256) void write_chpm(const int* __restrict__ cluster,
                                                  const int* __restrict__ counts,
                                                  const int* __restrict__ mis_flag,
                                                  float* __restrict__ out_ch,
                                                  float* __restrict__ out_pinv,
                                                  float* __restrict__ out_mis,
                                                  float* __restrict__ out_xp) {
  int idx = blockIdx.x * 256 + threadIdx.x;  // over N*N
  int a = idx >> 11, b = idx & (NN - 1);
  out_ch[idx] = (cluster[a] == b) ? 1.f : 0.f;
  float pv = 0.f;
  if (cluster[b] == a) {
    int c = counts[a];
    pv = 1.f / (float)(c > 0 ? c : 1);
  }
  out_pinv[idx] = pv;
  if (idx < NN) out_mis[idx] = mis_flag[idx] ? 1.f : 0.f;
  if (idx < NN * DD) {
    int c = counts[idx >> 9];
    out_xp[idx] = out_xp[idx] / (float)(c > 0 ? c : 1);
  }
}

// ---------------------------------------------------------------------------
extern "C" void kernel_launch(void* const* d_in, const int* in_sizes, int n_in,
                              void* d_out, int out_size, void* d_ws, size_t ws_size,
                              hipStream_t stream) {
  const int*   edge_index = (const int*)d_in[0];
  const float* edge_attr  = (const float*)d_in[1];
  const float* x          = (const float*)d_in[2];
  const int*   rank       = (const int*)d_in[3];
  const float* u          = (const float*)d_in[4];
  float* out              = (float*)d_out;  // f32 outputs, concatenated

  const int* row = edge_index;
  const int* col = edge_index + EE;

  float* out_adjc = out;                 // N*N — doubles as adj/rw scratch
  float* out_ch   = out + SZ;            // N*N — doubles as Bc scratch
  float* out_pinv = out + 2 * SZ;        // N*N
  float* out_mis  = out + 3 * SZ;        // N
  float* out_xp   = out + 3 * SZ + NN;   // N*D

  // d_ws layout (~490 KB). First 5 arrays zeroed; rest fully written.
  unsigned long long* packed = (unsigned long long*)d_ws;  // N u64 (zeroed)
  float* rowsum    = (float*)(packed + NN);        // N  (zeroed)
  int*   counts    = (int*)(rowsum + NN);          // N  (zeroed)
  int*   degree    = counts + NN;                  // N  (zeroed)
  int*   cdeg      = degree + NN;                  // N  (zeroed)
  int*   mis_flag  = cdeg + NN;                    // N
  int*   cluster   = mis_flag + NN;                // N
  int*   mis_list  = cluster + NN;                 // N
  int*   misinv    = mis_list + NN;                // N
  int*   mis_count = misinv + NN;                  // 1
  int*   fill_ptr  = mis_count + 1;                // N
  int*   cfill_ptr = fill_ptr + NN;                // N
  int*   row_ptr   = cfill_ptr + NN;               // N+1
  int*   col_ptr   = row_ptr + NN + 1;             // N+1
  unsigned short* colidx =                          // padded E (<=98304) u16, 32B-aligned
      (unsigned short*)(((uintptr_t)(col_ptr + NN + 1) + 31) & ~(uintptr_t)31);
  unsigned short* rowidx = colidx + 98304;         // padded E u16 (32B-aligned)

  hipMemsetAsync(out_adjc, 0, SZ * sizeof(float), stream);
  hipMemsetAsync(out_xp, 0, (size_t)NN * DD * sizeof(float), stream);
  hipMemsetAsync(d_ws, 0, NN * sizeof(unsigned long long) + 4 * NN * sizeof(int), stream);

  build_adj<<<EE / 256, 256, 0, stream>>>(row, col, edge_attr, out_adjc, rowsum, degree, cdeg);
  csr_scan_pad<<<1, 1024, 0, stream>>>(degree, cdeg, row_ptr, fill_ptr, col_ptr, cfill_ptr,
                                       colidx, rowidx);
  csr_fill<<<EE / 256, 256, 0, stream>>>(row, col, fill_ptr, cfill_ptr, colidx, rowidx);
  mis_kernel<<<1, 1024, 0, stream>>>(row_ptr, col_ptr, colidx, rowidx, rank,
                                     mis_flag, mis_list, misinv, mis_count);
  rw_transform_gather<<<(NN * NN) / 256, 256, 0, stream>>>(out_adjc, rowsum, misinv, out_ch);
  c2_argmax<<<1024, 256, 0, stream>>>(out_adjc, out_ch, u, mis_list, mis_count, packed);
  cluster_decode<<<NN / 256, 256, 0, stream>>>(packed, cluster, counts);

  // rw no longer needed: rewrite the region with the real adj_c
  hipMemsetAsync(out_adjc, 0, SZ * sizeof(float), stream);
  scatter_fused<<<(NN * DD) / 256, 256, 0, stream>>>(row, col, edge_attr, x, cluster,
                                                     out_adjc, out_xp);

  write_chpm<<<(NN * NN) / 256, 256, 0, stream>>>(cluster, counts, mis_flag,
                                                  out_ch, out_pinv, out_mis, out_xp);
}